// Round 2
// baseline (455.093 us; speedup 1.0000x reference)
//
#include <hip/hip_runtime.h>
#include <hip/hip_bf16.h>

typedef __attribute__((ext_vector_type(4))) float f32x4;
typedef __attribute__((ext_vector_type(8))) short s16x8;

#define MFMA(a,b,c) __builtin_amdgcn_mfma_f32_16x16x32_bf16(a,b,c,0,0,0)

__device__ __forceinline__ void gll16(const void* gptr, void* lptr){
  auto g = (const __attribute__((address_space(1))) unsigned int*)gptr;
  auto l = (__attribute__((address_space(3))) unsigned int*)lptr;
  __builtin_amdgcn_global_load_lds(g, l, 16, 0, 0);
}

__device__ __forceinline__ void split2(float x, __hip_bfloat16& h, __hip_bfloat16& l){
  h = __float2bfloat16(x);
  l = __float2bfloat16(x - __bfloat162float(h));
}

// ---------------- input split: fp32 -> (hi, lo) bf16 ----------------
__global__ void split_kernel(const float* __restrict__ in, __hip_bfloat16* __restrict__ hi,
                             __hip_bfloat16* __restrict__ lo, int n){
  int i = blockIdx.x*256 + threadIdx.x;
  if (i < n){
    float x = in[i];
    __hip_bfloat16 h, l;
    split2(x, h, l);
    hi[i] = h; lo[i] = l;
  }
}

// ---------------- NT GEMM (A[4096x768] x B[768x768]^T), split-bf16 ----------------
// BM=128, BN=64, BK=64. 4 waves, wave w owns rows [w*32, w*32+32).
// mode 0: Q epilogue  (scale, split -> [B,H,S,d] hi/lo)
// mode 1: K epilogue  (split -> [B,H,S,d] hi/lo)
// mode 2: V epilogue  (bf16 -> [B,H,d,S] transposed)
// mode 3: O epilogue  (fp32 -> [4096,768])
__global__ __launch_bounds__(256) void gemm_nt(
    const __hip_bfloat16* __restrict__ Ah, const __hip_bfloat16* __restrict__ Al,
    const __hip_bfloat16* __restrict__ Bh, const __hip_bfloat16* __restrict__ Bl,
    const float* __restrict__ bias, float scale, int mode,
    __hip_bfloat16* __restrict__ o_hi, __hip_bfloat16* __restrict__ o_lo,
    float* __restrict__ o_f)
{
  __shared__ __align__(16) __hip_bfloat16 sAh[128*64];
  __shared__ __align__(16) __hip_bfloat16 sAl[128*64];
  __shared__ __align__(16) __hip_bfloat16 sBh[64*64];
  __shared__ __align__(16) __hip_bfloat16 sBl[64*64];

  const int tid = threadIdx.x;
  const int w = tid >> 6, lane = tid & 63, r = lane & 15, g = lane >> 4;
  const int tm = blockIdx.x / 12, tn = blockIdx.x % 12;

  const char* gA_h = (const char*)Ah + (size_t)tm*128*768*2;
  const char* gA_l = (const char*)Al + (size_t)tm*128*768*2;
  const char* gB_h = (const char*)Bh + (size_t)tn*64*768*2;
  const char* gB_l = (const char*)Bl + (size_t)tn*64*768*2;

  f32x4 acc[2][4] = {};

  for (int kb = 0; kb < 768; kb += 64){
    __syncthreads();
    #pragma unroll
    for (int i = 0; i < 4; ++i){   // A tiles: 128 rows x 128B, row stride 1536B
      int lb = i*4096 + tid*16;
      int row = lb >> 7, colb = lb & 127;
      gll16(gA_h + (size_t)row*1536 + kb*2 + colb, (char*)sAh + i*4096 + w*1024);
      gll16(gA_l + (size_t)row*1536 + kb*2 + colb, (char*)sAl + i*4096 + w*1024);
    }
    #pragma unroll
    for (int i = 0; i < 2; ++i){   // B tiles: 64 rows x 128B
      int lb = i*4096 + tid*16;
      int row = lb >> 7, colb = lb & 127;
      gll16(gB_h + (size_t)row*1536 + kb*2 + colb, (char*)sBh + i*4096 + w*1024);
      gll16(gB_l + (size_t)row*1536 + kb*2 + colb, (char*)sBl + i*4096 + w*1024);
    }
    __syncthreads();
    #pragma unroll
    for (int c = 0; c < 2; ++c){
      s16x8 a_h[2], a_l[2];
      #pragma unroll
      for (int i = 0; i < 2; ++i){
        int off = (w*32 + i*16 + r)*64 + c*32 + g*8;
        a_h[i] = *(const s16x8*)(sAh + off);
        a_l[i] = *(const s16x8*)(sAl + off);
      }
      #pragma unroll
      for (int j = 0; j < 4; ++j){
        int off = (j*16 + r)*64 + c*32 + g*8;
        s16x8 b_h = *(const s16x8*)(sBh + off);
        s16x8 b_l = *(const s16x8*)(sBl + off);
        #pragma unroll
        for (int i = 0; i < 2; ++i){
          acc[i][j] = MFMA(a_h[i], b_h, acc[i][j]);
          acc[i][j] = MFMA(a_l[i], b_h, acc[i][j]);
          acc[i][j] = MFMA(a_h[i], b_l, acc[i][j]);
        }
      }
    }
  }

  #pragma unroll
  for (int i = 0; i < 2; ++i){
    #pragma unroll
    for (int j = 0; j < 4; ++j){
      #pragma unroll
      for (int e = 0; e < 4; ++e){
        int m = tm*128 + w*32 + i*16 + g*4 + e;   // row in [4096]
        int n = tn*64 + j*16 + r;                 // out feature in [768]
        float v = acc[i][j][e] + bias[n];
        if (mode <= 1){
          v *= scale;
          __hip_bfloat16 h, l; split2(v, h, l);
          int b = m >> 11, s = m & 2047;
          size_t idx = ((size_t)(b*12 + (n>>6))*2048 + s)*64 + (n & 63);
          o_hi[idx] = h; o_lo[idx] = l;
        } else if (mode == 2){
          int b = m >> 11, s = m & 2047;
          size_t idx = ((size_t)(b*12 + (n>>6))*64 + (n & 63))*2048 + s;
          o_hi[idx] = __float2bfloat16(v);
        } else {
          o_f[(size_t)m*768 + n] = v;
        }
      }
    }
  }
}

// ---------------- logits for one 64x64 tile (identical in both sweeps) ----------------
__device__ __forceinline__ void compute_logits(f32x4 lg[4],
    const __hip_bfloat16* sKh, const __hip_bfloat16* sKl,
    const s16x8 qfh[2], const s16x8 qfl[2], int r, int g){
  #pragma unroll
  for (int j = 0; j < 4; ++j){ lg[j][0]=0.f; lg[j][1]=0.f; lg[j][2]=0.f; lg[j][3]=0.f; }
  #pragma unroll
  for (int c = 0; c < 2; ++c){
    #pragma unroll
    for (int j = 0; j < 4; ++j){
      int off = (j*16 + r)*64 + c*32 + g*8;
      s16x8 b_h = *(const s16x8*)(sKh + off);
      s16x8 b_l = *(const s16x8*)(sKl + off);
      lg[j] = MFMA(qfh[c], b_h, lg[j]);
      lg[j] = MFMA(qfl[c], b_h, lg[j]);
      lg[j] = MFMA(qfh[c], b_l, lg[j]);
    }
  }
}

// ---------------- fused attention: two-sweep online softmax + weights write + PV ----------------
// grid = 24 (b,h) * 32 q-tiles; 4 waves; wave w owns q rows [qt*64 + w*16, +16)
__global__ __launch_bounds__(256) void attn_kernel(
    const __hip_bfloat16* __restrict__ qh, const __hip_bfloat16* __restrict__ ql,
    const __hip_bfloat16* __restrict__ kh, const __hip_bfloat16* __restrict__ kl,
    const __hip_bfloat16* __restrict__ vT,
    float* __restrict__ wout,
    __hip_bfloat16* __restrict__ attnh, __hip_bfloat16* __restrict__ attnl)
{
  __shared__ __align__(16) __hip_bfloat16 sQh[64*64];
  __shared__ __align__(16) __hip_bfloat16 sQl[64*64];
  __shared__ __align__(16) __hip_bfloat16 sKh[64*64];
  __shared__ __align__(16) __hip_bfloat16 sKl[64*64];
  __shared__ __align__(16) __hip_bfloat16 sW[4][16*64];

  const int tid = threadIdx.x;
  const int w = tid >> 6, lane = tid & 63, r = lane & 15, g = lane >> 4;
  const int bh = blockIdx.x >> 5, qt = blockIdx.x & 31;

  const char* qbase_h = (const char*)(qh + ((size_t)bh*2048 + qt*64)*64);
  const char* qbase_l = (const char*)(ql + ((size_t)bh*2048 + qt*64)*64);
  #pragma unroll
  for (int i = 0; i < 2; ++i){
    gll16(qbase_h + i*4096 + tid*16, (char*)sQh + i*4096 + w*1024);
    gll16(qbase_l + i*4096 + tid*16, (char*)sQl + i*4096 + w*1024);
  }
  __syncthreads();
  s16x8 qfh[2], qfl[2];
  #pragma unroll
  for (int c = 0; c < 2; ++c){
    int off = (w*16 + r)*64 + c*32 + g*8;
    qfh[c] = *(const s16x8*)(sQh + off);
    qfl[c] = *(const s16x8*)(sQl + off);
  }

  float m_[4], l_[4];
  #pragma unroll
  for (int e = 0; e < 4; ++e){ m_[e] = -INFINITY; l_[e] = 0.f; }

  const char* kbh = (const char*)(kh + (size_t)bh*2048*64);
  const char* kbl = (const char*)(kl + (size_t)bh*2048*64);

  // ---- sweep 1: exact row max / sumexp ----
  for (int kt = 0; kt < 32; ++kt){
    __syncthreads();
    #pragma unroll
    for (int i = 0; i < 2; ++i){
      gll16(kbh + (size_t)kt*8192 + i*4096 + tid*16, (char*)sKh + i*4096 + w*1024);
      gll16(kbl + (size_t)kt*8192 + i*4096 + tid*16, (char*)sKl + i*4096 + w*1024);
    }
    __syncthreads();
    f32x4 lg[4];
    compute_logits(lg, sKh, sKl, qfh, qfl, r, g);
    #pragma unroll
    for (int e = 0; e < 4; ++e){
      float v = fmaxf(fmaxf(lg[0][e], lg[1][e]), fmaxf(lg[2][e], lg[3][e]));
      v = fmaxf(v, __shfl_xor(v, 1));
      v = fmaxf(v, __shfl_xor(v, 2));
      v = fmaxf(v, __shfl_xor(v, 4));
      v = fmaxf(v, __shfl_xor(v, 8));
      float mn = fmaxf(m_[e], v);
      float s = __expf(lg[0][e]-mn) + __expf(lg[1][e]-mn)
              + __expf(lg[2][e]-mn) + __expf(lg[3][e]-mn);
      s += __shfl_xor(s, 1); s += __shfl_xor(s, 2);
      s += __shfl_xor(s, 4); s += __shfl_xor(s, 8);
      l_[e] = l_[e]*__expf(m_[e]-mn) + s;
      m_[e] = mn;
    }
  }

  float rl_[4];
  #pragma unroll
  for (int e = 0; e < 4; ++e) rl_[e] = 1.0f / l_[e];

  // ---- sweep 2: recompute logits, write weights, PV ----
  f32x4 pv[4] = {};
  const char* vb = (const char*)(vT + (size_t)bh*64*2048);
  size_t wbase_row = (size_t)bh*2048*2048 + ((size_t)qt*64 + w*16)*2048;
  __hip_bfloat16* sWp = sW[w];

  for (int kt = 0; kt < 32; ++kt){
    __syncthreads();
    #pragma unroll
    for (int i = 0; i < 2; ++i){
      gll16(kbh + (size_t)kt*8192 + i*4096 + tid*16, (char*)sKh + i*4096 + w*1024);
      gll16(kbl + (size_t)kt*8192 + i*4096 + tid*16, (char*)sKl + i*4096 + w*1024);
    }
    __syncthreads();
    f32x4 lg[4];
    compute_logits(lg, sKh, sKl, qfh, qfl, r, g);
    #pragma unroll
    for (int j = 0; j < 4; ++j){
      #pragma unroll
      for (int e = 0; e < 4; ++e){
        float wv = __expf(lg[j][e] - m_[e]) * rl_[e];
        wout[wbase_row + (size_t)(g*4+e)*2048 + kt*64 + j*16 + r] = wv;
        sWp[(g*4+e)*64 + j*16 + r] = __float2bfloat16(wv);
      }
    }
    asm volatile("s_waitcnt lgkmcnt(0)" ::: "memory");
    #pragma unroll
    for (int c = 0; c < 2; ++c){
      s16x8 wa = *(const s16x8*)(sWp + r*64 + c*32 + g*8);
      #pragma unroll
      for (int dt = 0; dt < 4; ++dt){
        s16x8 vv = *(const s16x8*)(vb + ((size_t)(dt*16 + r)*2048 + kt*64 + c*32 + g*8)*2);
        pv[dt] = MFMA(wa, vv, pv[dt]);
      }
    }
  }

  const int b_ = bh / 12, hh = bh % 12;
  #pragma unroll
  for (int dt = 0; dt < 4; ++dt){
    #pragma unroll
    for (int e = 0; e < 4; ++e){
      float av = pv[dt][e];
      int srow = qt*64 + w*16 + g*4 + e;
      int ncol = hh*64 + dt*16 + r;
      size_t idx = ((size_t)b_*2048 + srow)*768 + ncol;
      __hip_bfloat16 h, l; split2(av, h, l);
      attnh[idx] = h; attnl[idx] = l;
    }
  }
}

// ---------------- launch ----------------
extern "C" void kernel_launch(void* const* d_in, const int* in_sizes, int n_in,
                              void* d_out, int out_size, void* d_ws, size_t ws_size,
                              hipStream_t stream){
  const float* Q  = (const float*)d_in[0];
  const float* Kx = (const float*)d_in[1];
  const float* V  = (const float*)d_in[2];
  const float* Wq = (const float*)d_in[3];
  const float* bq = (const float*)d_in[4];
  const float* Wk = (const float*)d_in[5];
  const float* bk = (const float*)d_in[6];
  const float* Wv = (const float*)d_in[7];
  const float* bv = (const float*)d_in[8];
  const float* Wo = (const float*)d_in[9];
  const float* bo = (const float*)d_in[10];

  float* out = (float*)d_out;
  float* wts = out + (size_t)2*2048*768;

  char* cur = (char*)d_ws;
  auto alloc = [&](size_t elems)->__hip_bfloat16*{
    __hip_bfloat16* p = (__hip_bfloat16*)cur;
    cur += ((elems*2 + 255) & ~(size_t)255);
    return p;
  };
  const size_t NE = (size_t)4096*768;
  const size_t WE = (size_t)768*768;

  __hip_bfloat16 *QIh=alloc(NE), *QIl=alloc(NE), *KIh=alloc(NE), *KIl=alloc(NE),
                 *VIh=alloc(NE), *VIl=alloc(NE);
  __hip_bfloat16 *Wqh=alloc(WE), *Wql=alloc(WE), *Wkh=alloc(WE), *Wkl=alloc(WE),
                 *Wvh=alloc(WE), *Wvl=alloc(WE), *Woh=alloc(WE), *Wol=alloc(WE);
  __hip_bfloat16 *qhp=alloc(NE), *qlp=alloc(NE), *khp=alloc(NE), *klp=alloc(NE),
                 *vTp=alloc(NE);
  __hip_bfloat16 *ath=alloc(NE), *atl=alloc(NE);

  int nb  = (int)((NE + 255)/256);
  int nbw = (int)((WE + 255)/256);
  split_kernel<<<nb, 256, 0, stream>>>(Q,  QIh, QIl, (int)NE);
  split_kernel<<<nb, 256, 0, stream>>>(Kx, KIh, KIl, (int)NE);
  split_kernel<<<nb, 256, 0, stream>>>(V,  VIh, VIl, (int)NE);
  split_kernel<<<nbw,256, 0, stream>>>(Wq, Wqh, Wql, (int)WE);
  split_kernel<<<nbw,256, 0, stream>>>(Wk, Wkh, Wkl, (int)WE);
  split_kernel<<<nbw,256, 0, stream>>>(Wv, Wvh, Wvl, (int)WE);
  split_kernel<<<nbw,256, 0, stream>>>(Wo, Woh, Wol, (int)WE);

  gemm_nt<<<384, 256, 0, stream>>>(QIh,QIl,Wqh,Wql,bq, 0.125f, 0, qhp,qlp,nullptr);
  gemm_nt<<<384, 256, 0, stream>>>(KIh,KIl,Wkh,Wkl,bk, 1.0f,   1, khp,klp,nullptr);
  gemm_nt<<<384, 256, 0, stream>>>(VIh,VIl,Wvh,Wvl,bv, 1.0f,   2, vTp,nullptr,nullptr);

  attn_kernel<<<768, 256, 0, stream>>>(qhp,qlp,khp,klp,vTp, wts, ath, atl);

  gemm_nt<<<384, 256, 0, stream>>>(ath,atl,Woh,Wol,bo, 1.0f, 3, nullptr,nullptr,out);
}

// Round 3
// 443.366 us; speedup vs baseline: 1.0265x; 1.0265x over previous
//
#include <hip/hip_runtime.h>
#include <hip/hip_bf16.h>

typedef __attribute__((ext_vector_type(4)))  float f32x4;
typedef __attribute__((ext_vector_type(16))) float f32x16;
typedef __attribute__((ext_vector_type(8)))  short s16x8;

#define MFMA(a,b,c)   __builtin_amdgcn_mfma_f32_16x16x32_bf16(a,b,c,0,0,0)
#define MFMA32(a,b,c) __builtin_amdgcn_mfma_f32_32x32x16_bf16(a,b,c,0,0,0)

__device__ __forceinline__ void gll16(const void* gptr, void* lptr){
  auto g = (const __attribute__((address_space(1))) unsigned int*)gptr;
  auto l = (__attribute__((address_space(3))) unsigned int*)lptr;
  __builtin_amdgcn_global_load_lds(g, l, 16, 0, 0);
}

__device__ __forceinline__ void split2(float x, __hip_bfloat16& h, __hip_bfloat16& l){
  h = __float2bfloat16(x);
  l = __float2bfloat16(x - __bfloat162float(h));
}

__device__ __forceinline__ unsigned short bf16bits(float x){
  __hip_bfloat16 h = __float2bfloat16(x);
  return *reinterpret_cast<unsigned short*>(&h);
}
__device__ __forceinline__ unsigned pack2(float lo, float hi){
  return (unsigned)bf16bits(lo) | ((unsigned)bf16bits(hi) << 16);
}
__device__ __forceinline__ void plane32swap(unsigned &a, unsigned &b){
  asm volatile("v_permlane32_swap_b32 %0, %1" : "+v"(a), "+v"(b));
}

// ---------------- input split: fp32 -> (hi, lo) bf16 ----------------
__global__ void split_kernel(const float* __restrict__ in, __hip_bfloat16* __restrict__ hi,
                             __hip_bfloat16* __restrict__ lo, int n){
  int i = blockIdx.x*256 + threadIdx.x;
  if (i < n){
    float x = in[i];
    __hip_bfloat16 h, l;
    split2(x, h, l);
    hi[i] = h; lo[i] = l;
  }
}

// ---------------- NT GEMM (A[4096x768] x B[768x768]^T), split-bf16 ----------------
__global__ __launch_bounds__(256) void gemm_nt(
    const __hip_bfloat16* __restrict__ Ah, const __hip_bfloat16* __restrict__ Al,
    const __hip_bfloat16* __restrict__ Bh, const __hip_bfloat16* __restrict__ Bl,
    const float* __restrict__ bias, float scale, int mode,
    __hip_bfloat16* __restrict__ o_hi, __hip_bfloat16* __restrict__ o_lo,
    float* __restrict__ o_f)
{
  __shared__ __align__(16) __hip_bfloat16 sAh[128*64];
  __shared__ __align__(16) __hip_bfloat16 sAl[128*64];
  __shared__ __align__(16) __hip_bfloat16 sBh[64*64];
  __shared__ __align__(16) __hip_bfloat16 sBl[64*64];

  const int tid = threadIdx.x;
  const int w = tid >> 6, lane = tid & 63, r = lane & 15, g = lane >> 4;
  const int tm = blockIdx.x / 12, tn = blockIdx.x % 12;

  const char* gA_h = (const char*)Ah + (size_t)tm*128*768*2;
  const char* gA_l = (const char*)Al + (size_t)tm*128*768*2;
  const char* gB_h = (const char*)Bh + (size_t)tn*64*768*2;
  const char* gB_l = (const char*)Bl + (size_t)tn*64*768*2;

  f32x4 acc[2][4] = {};

  for (int kb = 0; kb < 768; kb += 64){
    __syncthreads();
    #pragma unroll
    for (int i = 0; i < 4; ++i){
      int lb = i*4096 + tid*16;
      int row = lb >> 7, colb = lb & 127;
      gll16(gA_h + (size_t)row*1536 + kb*2 + colb, (char*)sAh + i*4096 + w*1024);
      gll16(gA_l + (size_t)row*1536 + kb*2 + colb, (char*)sAl + i*4096 + w*1024);
    }
    #pragma unroll
    for (int i = 0; i < 2; ++i){
      int lb = i*4096 + tid*16;
      int row = lb >> 7, colb = lb & 127;
      gll16(gB_h + (size_t)row*1536 + kb*2 + colb, (char*)sBh + i*4096 + w*1024);
      gll16(gB_l + (size_t)row*1536 + kb*2 + colb, (char*)sBl + i*4096 + w*1024);
    }
    __syncthreads();
    #pragma unroll
    for (int c = 0; c < 2; ++c){
      s16x8 a_h[2], a_l[2];
      #pragma unroll
      for (int i = 0; i < 2; ++i){
        int off = (w*32 + i*16 + r)*64 + c*32 + g*8;
        a_h[i] = *(const s16x8*)(sAh + off);
        a_l[i] = *(const s16x8*)(sAl + off);
      }
      #pragma unroll
      for (int j = 0; j < 4; ++j){
        int off = (j*16 + r)*64 + c*32 + g*8;
        s16x8 b_h = *(const s16x8*)(sBh + off);
        s16x8 b_l = *(const s16x8*)(sBl + off);
        #pragma unroll
        for (int i = 0; i < 2; ++i){
          acc[i][j] = MFMA(a_h[i], b_h, acc[i][j]);
          acc[i][j] = MFMA(a_l[i], b_h, acc[i][j]);
          acc[i][j] = MFMA(a_h[i], b_l, acc[i][j]);
        }
      }
    }
  }

  #pragma unroll
  for (int i = 0; i < 2; ++i){
    #pragma unroll
    for (int j = 0; j < 4; ++j){
      #pragma unroll
      for (int e = 0; e < 4; ++e){
        int m = tm*128 + w*32 + i*16 + g*4 + e;
        int n = tn*64 + j*16 + r;
        float v = acc[i][j][e] + bias[n];
        if (mode <= 1){
          v *= scale;
          __hip_bfloat16 h, l; split2(v, h, l);
          int b = m >> 11, s = m & 2047;
          size_t idx = ((size_t)(b*12 + (n>>6))*2048 + s)*64 + (n & 63);
          o_hi[idx] = h; o_lo[idx] = l;
        } else if (mode == 2){
          int b = m >> 11, s = m & 2047;
          size_t idx = ((size_t)(b*12 + (n>>6))*64 + (n & 63))*2048 + s;
          o_hi[idx] = __float2bfloat16(v);
        } else {
          o_f[(size_t)m*768 + n] = v;
        }
      }
    }
  }
}

// ---------------- S^T tile for one kt (64 keys x 32 q), identical in both sweeps ----------------
// s0: keys [kt*64, +32), s1: keys [kt*64+32, +64). Lane holds q = lane&31 column.
__device__ __forceinline__ void qk_tile(f32x16& s0, f32x16& s1,
    const __hip_bfloat16* __restrict__ kb_h, const __hip_bfloat16* __restrict__ kb_l,
    int kt, int col, int hi, const s16x8 Qh[4], const s16x8 Ql[4])
{
  #pragma unroll
  for (int e = 0; e < 16; ++e){ s0[e] = 0.f; s1[e] = 0.f; }
  const __hip_bfloat16* r0h = kb_h + ((size_t)kt*64 + col)*64      + hi*8;
  const __hip_bfloat16* r0l = kb_l + ((size_t)kt*64 + col)*64      + hi*8;
  const __hip_bfloat16* r1h = kb_h + ((size_t)kt*64 + 32 + col)*64 + hi*8;
  const __hip_bfloat16* r1l = kb_l + ((size_t)kt*64 + 32 + col)*64 + hi*8;
  s16x8 k0h[4], k0l[4], k1h[4], k1l[4];
  #pragma unroll
  for (int ks = 0; ks < 4; ++ks){
    k0h[ks] = *(const s16x8*)(r0h + ks*16);
    k0l[ks] = *(const s16x8*)(r0l + ks*16);
    k1h[ks] = *(const s16x8*)(r1h + ks*16);
    k1l[ks] = *(const s16x8*)(r1l + ks*16);
  }
  #pragma unroll
  for (int ks = 0; ks < 4; ++ks){
    s0 = MFMA32(k0h[ks], Qh[ks], s0);
    s0 = MFMA32(k0l[ks], Qh[ks], s0);
    s0 = MFMA32(k0h[ks], Ql[ks], s0);
    s1 = MFMA32(k1h[ks], Qh[ks], s1);
    s1 = MFMA32(k1l[ks], Qh[ks], s1);
    s1 = MFMA32(k1h[ks], Ql[ks], s1);
  }
}

// ---------------- fused attention: swapped 32x32, zero-LDS, zero-barrier ----------------
// grid = 24 bh * 64 q-tiles of 32 rows; block = 1 wave. Lane owns q = qt*32 + (lane&31).
__global__ __launch_bounds__(64) void attn_kernel(
    const __hip_bfloat16* __restrict__ qh, const __hip_bfloat16* __restrict__ ql,
    const __hip_bfloat16* __restrict__ kh, const __hip_bfloat16* __restrict__ kl,
    const __hip_bfloat16* __restrict__ vT,
    float* __restrict__ wout,
    __hip_bfloat16* __restrict__ attnh, __hip_bfloat16* __restrict__ attnl)
{
  const int lane = threadIdx.x & 63;
  const int col = lane & 31;
  const int hi  = lane >> 5;
  const int bh = blockIdx.x >> 6, qt = blockIdx.x & 63;

  // Q fragments straight from global (row-major [bh][s][64])
  const __hip_bfloat16* qr_h = qh + ((size_t)bh*2048 + qt*32 + col)*64 + hi*8;
  const __hip_bfloat16* qr_l = ql + ((size_t)bh*2048 + qt*32 + col)*64 + hi*8;
  s16x8 Qh[4], Ql[4];
  #pragma unroll
  for (int ks = 0; ks < 4; ++ks){
    Qh[ks] = *(const s16x8*)(qr_h + ks*16);
    Ql[ks] = *(const s16x8*)(qr_l + ks*16);
  }

  const __hip_bfloat16* kb_h = kh + (size_t)bh*2048*64;
  const __hip_bfloat16* kb_l = kl + (size_t)bh*2048*64;

  float m_run = -INFINITY, l_run = 0.f;

  // ---- sweep 1: per-lane online max/sum over this lane's 1024 keys ----
  for (int kt = 0; kt < 32; ++kt){
    f32x16 s0, s1;
    qk_tile(s0, s1, kb_h, kb_l, kt, col, hi, Qh, Ql);
    float mx = s0[0];
    #pragma unroll
    for (int e = 1; e < 16; ++e) mx = fmaxf(mx, s0[e]);
    #pragma unroll
    for (int e = 0; e < 16; ++e) mx = fmaxf(mx, s1[e]);
    float mn = fmaxf(m_run, mx);
    float sum = 0.f;
    #pragma unroll
    for (int e = 0; e < 16; ++e) sum += __expf(s0[e]-mn);
    #pragma unroll
    for (int e = 0; e < 16; ++e) sum += __expf(s1[e]-mn);
    l_run = l_run*__expf(m_run-mn) + sum;
    m_run = mn;
  }
  // merge with partner lane (lane ^ 32 holds the other half of each q-row)
  {
    float mo = __shfl_xor(m_run, 32);
    float lo = __shfl_xor(l_run, 32);
    float mt = fmaxf(m_run, mo);
    l_run = l_run*__expf(m_run-mt) + lo*__expf(mo-mt);
    m_run = mt;
  }
  const float rl = 1.0f / l_run;

  // ---- sweep 2: recompute S (bitwise identical), write weights, PV ----
  f32x16 pv0, pv1;
  #pragma unroll
  for (int e = 0; e < 16; ++e){ pv0[e] = 0.f; pv1[e] = 0.f; }
  const __hip_bfloat16* vb = vT + (size_t)bh*64*2048;
  float* wq = wout + (((size_t)bh*2048 + qt*32 + col)*2048);

  for (int kt = 0; kt < 32; ++kt){
    f32x16 s0, s1;
    qk_tile(s0, s1, kb_h, kb_l, kt, col, hi, Qh, Ql);
    float w_[32];
    #pragma unroll
    for (int e = 0; e < 16; ++e){
      w_[e]    = __expf(s0[e]-m_run)*rl;
      w_[16+e] = __expf(s1[e]-m_run)*rl;
    }
    // weights: lane's keys = kt*64 + t*32 + 8*rq + 4*hi + [0..3]
    float* wk = wq + kt*64;
    #pragma unroll
    for (int t = 0; t < 2; ++t){
      #pragma unroll
      for (int rq = 0; rq < 4; ++rq){
        float4 f = make_float4(w_[t*16+rq*4+0], w_[t*16+rq*4+1],
                               w_[t*16+rq*4+2], w_[t*16+rq*4+3]);
        *(float4*)(wk + t*32 + rq*8 + hi*4) = f;
      }
    }
    // P fragments (per 16-key window) + PV
    #pragma unroll
    for (int ww = 0; ww < 4; ++ww){
      int e0 = (ww>>1)*16 + (ww&1)*8;
      unsigned wa = pack2(w_[e0+0], w_[e0+1]);
      unsigned wb = pack2(w_[e0+2], w_[e0+3]);
      unsigned wc = pack2(w_[e0+4], w_[e0+5]);
      unsigned wd = pack2(w_[e0+6], w_[e0+7]);
      plane32swap(wa, wc);
      plane32swap(wb, wd);
      union { unsigned u[4]; s16x8 v; } cv;
      cv.u[0] = wa; cv.u[1] = wb; cv.u[2] = wc; cv.u[3] = wd;
      s16x8 af = cv.v;
      #pragma unroll
      for (int dt = 0; dt < 2; ++dt){
        s16x8 vv = *(const s16x8*)(vb + ((size_t)(dt*32+col)*2048 + kt*64 + ww*16 + hi*8));
        if (dt == 0) pv0 = MFMA32(af, vv, pv0);
        else         pv1 = MFMA32(af, vv, pv1);
      }
    }
  }

  // ---- epilogue: attn output (hi/lo split) to [b][s][768] ----
  const int b_ = bh / 12, hh = bh % 12;
  #pragma unroll
  for (int e = 0; e < 16; ++e){
    int qrow = qt*32 + (e&3) + 8*(e>>2) + 4*hi;
    size_t base = ((size_t)b_*2048 + qrow)*768 + hh*64;
    __hip_bfloat16 h0, l0, h1, l1;
    split2(pv0[e], h0, l0);
    split2(pv1[e], h1, l1);
    attnh[base + col]      = h0; attnl[base + col]      = l0;
    attnh[base + 32 + col] = h1; attnl[base + 32 + col] = l1;
  }
}

// ---------------- launch ----------------
extern "C" void kernel_launch(void* const* d_in, const int* in_sizes, int n_in,
                              void* d_out, int out_size, void* d_ws, size_t ws_size,
                              hipStream_t stream){
  const float* Q  = (const float*)d_in[0];
  const float* Kx = (const float*)d_in[1];
  const float* V  = (const float*)d_in[2];
  const float* Wq = (const float*)d_in[3];
  const float* bq = (const float*)d_in[4];
  const float* Wk = (const float*)d_in[5];
  const float* bk = (const float*)d_in[6];
  const float* Wv = (const float*)d_in[7];
  const float* bv = (const float*)d_in[8];
  const float* Wo = (const float*)d_in[9];
  const float* bo = (const float*)d_in[10];

  float* out = (float*)d_out;
  float* wts = out + (size_t)2*2048*768;

  char* cur = (char*)d_ws;
  auto alloc = [&](size_t elems)->__hip_bfloat16*{
    __hip_bfloat16* p = (__hip_bfloat16*)cur;
    cur += ((elems*2 + 255) & ~(size_t)255);
    return p;
  };
  const size_t NE = (size_t)4096*768;
  const size_t WE = (size_t)768*768;

  __hip_bfloat16 *QIh=alloc(NE), *QIl=alloc(NE), *KIh=alloc(NE), *KIl=alloc(NE),
                 *VIh=alloc(NE), *VIl=alloc(NE);
  __hip_bfloat16 *Wqh=alloc(WE), *Wql=alloc(WE), *Wkh=alloc(WE), *Wkl=alloc(WE),
                 *Wvh=alloc(WE), *Wvl=alloc(WE), *Woh=alloc(WE), *Wol=alloc(WE);
  __hip_bfloat16 *qhp=alloc(NE), *qlp=alloc(NE), *khp=alloc(NE), *klp=alloc(NE),
                 *vTp=alloc(NE);
  __hip_bfloat16 *ath=alloc(NE), *atl=alloc(NE);

  int nb  = (int)((NE + 255)/256);
  int nbw = (int)((WE + 255)/256);
  split_kernel<<<nb, 256, 0, stream>>>(Q,  QIh, QIl, (int)NE);
  split_kernel<<<nb, 256, 0, stream>>>(Kx, KIh, KIl, (int)NE);
  split_kernel<<<nb, 256, 0, stream>>>(V,  VIh, VIl, (int)NE);
  split_kernel<<<nbw,256, 0, stream>>>(Wq, Wqh, Wql, (int)WE);
  split_kernel<<<nbw,256, 0, stream>>>(Wk, Wkh, Wkl, (int)WE);
  split_kernel<<<nbw,256, 0, stream>>>(Wv, Wvh, Wvl, (int)WE);
  split_kernel<<<nbw,256, 0, stream>>>(Wo, Woh, Wol, (int)WE);

  gemm_nt<<<384, 256, 0, stream>>>(QIh,QIl,Wqh,Wql,bq, 0.125f, 0, qhp,qlp,nullptr);
  gemm_nt<<<384, 256, 0, stream>>>(KIh,KIl,Wkh,Wkl,bk, 1.0f,   1, khp,klp,nullptr);
  gemm_nt<<<384, 256, 0, stream>>>(VIh,VIl,Wvh,Wvl,bv, 1.0f,   2, vTp,nullptr,nullptr);

  attn_kernel<<<1536, 64, 0, stream>>>(qhp,qlp,khp,klp,vTp, wts, ath, atl);

  gemm_nt<<<384, 256, 0, stream>>>(ath,atl,Woh,Wol,bo, 1.0f, 3, nullptr,nullptr,out);
}

// Round 4
// 434.116 us; speedup vs baseline: 1.0483x; 1.0213x over previous
//
#include <hip/hip_runtime.h>
#include <hip/hip_bf16.h>

typedef __attribute__((ext_vector_type(4)))  float f32x4;
typedef __attribute__((ext_vector_type(16))) float f32x16;
typedef __attribute__((ext_vector_type(8)))  short s16x8;

#define MFMA(a,b,c)   __builtin_amdgcn_mfma_f32_16x16x32_bf16(a,b,c,0,0,0)
#define MFMA32(a,b,c) __builtin_amdgcn_mfma_f32_32x32x16_bf16(a,b,c,0,0,0)

__device__ __forceinline__ void gll16(const void* gptr, void* lptr){
  auto g = (const __attribute__((address_space(1))) unsigned int*)gptr;
  auto l = (__attribute__((address_space(3))) unsigned int*)lptr;
  __builtin_amdgcn_global_load_lds(g, l, 16, 0, 0);
}

__device__ __forceinline__ void split2(float x, __hip_bfloat16& h, __hip_bfloat16& l){
  h = __float2bfloat16(x);
  l = __float2bfloat16(x - __bfloat162float(h));
}

__device__ __forceinline__ unsigned short bf16bits(float x){
  __hip_bfloat16 h = __float2bfloat16(x);
  return *reinterpret_cast<unsigned short*>(&h);
}
__device__ __forceinline__ unsigned pack2(float lo, float hi){
  return (unsigned)bf16bits(lo) | ((unsigned)bf16bits(hi) << 16);
}
__device__ __forceinline__ void plane32swap(unsigned &a, unsigned &b){
  asm volatile("v_permlane32_swap_b32 %0, %1" : "+v"(a), "+v"(b));
}

// ---------------- fused input split: fp32 -> (hi, lo) bf16, float4-vectorized ----------------
// segments: Q,K,V (NE each) then Wq,Wk,Wv,Wo (WE each), all /4 element counts
__global__ __launch_bounds__(256) void split_all(
  const float* __restrict__ Q, const float* __restrict__ K, const float* __restrict__ V,
  const float* __restrict__ Wq, const float* __restrict__ Wk,
  const float* __restrict__ Wv, const float* __restrict__ Wo,
  __hip_bfloat16* __restrict__ QIh, __hip_bfloat16* __restrict__ QIl,
  __hip_bfloat16* __restrict__ KIh, __hip_bfloat16* __restrict__ KIl,
  __hip_bfloat16* __restrict__ VIh, __hip_bfloat16* __restrict__ VIl,
  __hip_bfloat16* __restrict__ Wqh, __hip_bfloat16* __restrict__ Wql,
  __hip_bfloat16* __restrict__ Wkh, __hip_bfloat16* __restrict__ Wkl,
  __hip_bfloat16* __restrict__ Wvh, __hip_bfloat16* __restrict__ Wvl,
  __hip_bfloat16* __restrict__ Woh, __hip_bfloat16* __restrict__ Wol)
{
  const int NE4 = 786432, WE4 = 147456;
  int i = blockIdx.x*256 + threadIdx.x;
  const float* src; __hip_bfloat16 *dh, *dl; int off;
  if (i < 3*NE4){
    int seg = i / NE4; off = i - seg*NE4;
    src = seg==0 ? Q   : (seg==1 ? K   : V);
    dh  = seg==0 ? QIh : (seg==1 ? KIh : VIh);
    dl  = seg==0 ? QIl : (seg==1 ? KIl : VIl);
  } else {
    int j = i - 3*NE4; int seg = j / WE4; off = j - seg*WE4;
    src = seg==0 ? Wq  : (seg==1 ? Wk  : (seg==2 ? Wv  : Wo));
    dh  = seg==0 ? Wqh : (seg==1 ? Wkh : (seg==2 ? Wvh : Woh));
    dl  = seg==0 ? Wql : (seg==1 ? Wkl : (seg==2 ? Wvl : Wol));
  }
  float4 x = ((const float4*)src)[off];
  __hip_bfloat16 h0,l0,h1,l1,h2,l2,h3,l3;
  split2(x.x,h0,l0); split2(x.y,h1,l1); split2(x.z,h2,l2); split2(x.w,h3,l3);
  union { __hip_bfloat16 b[4]; ushort4 u; } H, L;
  H.b[0]=h0; H.b[1]=h1; H.b[2]=h2; H.b[3]=h3;
  L.b[0]=l0; L.b[1]=l1; L.b[2]=l2; L.b[3]=l3;
  *(ushort4*)(dh + (size_t)off*4) = H.u;
  *(ushort4*)(dl + (size_t)off*4) = L.u;
}

// ---------------- NT GEMM (A[4096x768] x B[768x768]^T), split-bf16 ----------------
__global__ __launch_bounds__(256) void gemm_nt(
    const __hip_bfloat16* __restrict__ Ah, const __hip_bfloat16* __restrict__ Al,
    const __hip_bfloat16* __restrict__ Bh, const __hip_bfloat16* __restrict__ Bl,
    const float* __restrict__ bias, float scale, int mode,
    __hip_bfloat16* __restrict__ o_hi, __hip_bfloat16* __restrict__ o_lo,
    float* __restrict__ o_f)
{
  __shared__ __align__(16) __hip_bfloat16 sAh[128*64];
  __shared__ __align__(16) __hip_bfloat16 sAl[128*64];
  __shared__ __align__(16) __hip_bfloat16 sBh[64*64];
  __shared__ __align__(16) __hip_bfloat16 sBl[64*64];

  const int tid = threadIdx.x;
  const int w = tid >> 6, lane = tid & 63, r = lane & 15, g = lane >> 4;
  const int tm = blockIdx.x / 12, tn = blockIdx.x % 12;

  const char* gA_h = (const char*)Ah + (size_t)tm*128*768*2;
  const char* gA_l = (const char*)Al + (size_t)tm*128*768*2;
  const char* gB_h = (const char*)Bh + (size_t)tn*64*768*2;
  const char* gB_l = (const char*)Bl + (size_t)tn*64*768*2;

  f32x4 acc[2][4] = {};

  for (int kb = 0; kb < 768; kb += 64){
    __syncthreads();
    #pragma unroll
    for (int i = 0; i < 4; ++i){
      int lb = i*4096 + tid*16;
      int row = lb >> 7, colb = lb & 127;
      gll16(gA_h + (size_t)row*1536 + kb*2 + colb, (char*)sAh + i*4096 + w*1024);
      gll16(gA_l + (size_t)row*1536 + kb*2 + colb, (char*)sAl + i*4096 + w*1024);
    }
    #pragma unroll
    for (int i = 0; i < 2; ++i){
      int lb = i*4096 + tid*16;
      int row = lb >> 7, colb = lb & 127;
      gll16(gB_h + (size_t)row*1536 + kb*2 + colb, (char*)sBh + i*4096 + w*1024);
      gll16(gB_l + (size_t)row*1536 + kb*2 + colb, (char*)sBl + i*4096 + w*1024);
    }
    __syncthreads();
    #pragma unroll
    for (int c = 0; c < 2; ++c){
      s16x8 a_h[2], a_l[2];
      #pragma unroll
      for (int i = 0; i < 2; ++i){
        int off = (w*32 + i*16 + r)*64 + c*32 + g*8;
        a_h[i] = *(const s16x8*)(sAh + off);
        a_l[i] = *(const s16x8*)(sAl + off);
      }
      #pragma unroll
      for (int j = 0; j < 4; ++j){
        int off = (j*16 + r)*64 + c*32 + g*8;
        s16x8 b_h = *(const s16x8*)(sBh + off);
        s16x8 b_l = *(const s16x8*)(sBl + off);
        #pragma unroll
        for (int i = 0; i < 2; ++i){
          acc[i][j] = MFMA(a_h[i], b_h, acc[i][j]);
          acc[i][j] = MFMA(a_l[i], b_h, acc[i][j]);
          acc[i][j] = MFMA(a_h[i], b_l, acc[i][j]);
        }
      }
    }
  }

  #pragma unroll
  for (int i = 0; i < 2; ++i){
    #pragma unroll
    for (int j = 0; j < 4; ++j){
      #pragma unroll
      for (int e = 0; e < 4; ++e){
        int m = tm*128 + w*32 + i*16 + g*4 + e;
        int n = tn*64 + j*16 + r;
        float v = acc[i][j][e] + bias[n];
        if (mode <= 1){
          v *= scale;
          __hip_bfloat16 h, l; split2(v, h, l);
          int b = m >> 11, s = m & 2047;
          size_t idx = ((size_t)(b*12 + (n>>6))*2048 + s)*64 + (n & 63);
          o_hi[idx] = h; o_lo[idx] = l;
        } else if (mode == 2){
          int b = m >> 11, s = m & 2047;
          size_t idx = ((size_t)(b*12 + (n>>6))*64 + (n & 63))*2048 + s;
          o_hi[idx] = __float2bfloat16(v);
        } else {
          o_f[(size_t)m*768 + n] = v;
        }
      }
    }
  }
}

// ---------------- attention: K-tile registers + MFMA ----------------
struct KT { s16x8 h0[4], l0[4], h1[4], l1[4]; };

__device__ __forceinline__ void kt_load(KT& t,
    const __hip_bfloat16* __restrict__ kb_h, const __hip_bfloat16* __restrict__ kb_l,
    int kt, int col, int hi){
  const __hip_bfloat16* r0h = kb_h + ((size_t)kt*64 + col)*64      + hi*8;
  const __hip_bfloat16* r0l = kb_l + ((size_t)kt*64 + col)*64      + hi*8;
  const __hip_bfloat16* r1h = kb_h + ((size_t)kt*64 + 32 + col)*64 + hi*8;
  const __hip_bfloat16* r1l = kb_l + ((size_t)kt*64 + 32 + col)*64 + hi*8;
  #pragma unroll
  for (int ks = 0; ks < 4; ++ks){
    t.h0[ks] = *(const s16x8*)(r0h + ks*16);
    t.l0[ks] = *(const s16x8*)(r0l + ks*16);
    t.h1[ks] = *(const s16x8*)(r1h + ks*16);
    t.l1[ks] = *(const s16x8*)(r1l + ks*16);
  }
}

// identical MFMA order in both sweeps -> bitwise-identical logits
__device__ __forceinline__ void kt_mfma(f32x16& s0, f32x16& s1, const KT& t,
    const s16x8 Qh[4], const s16x8 Ql[4]){
  #pragma unroll
  for (int e = 0; e < 16; ++e){ s0[e]=0.f; s1[e]=0.f; }
  #pragma unroll
  for (int ks = 0; ks < 4; ++ks){
    s0 = MFMA32(t.h0[ks], Qh[ks], s0);
    s0 = MFMA32(t.l0[ks], Qh[ks], s0);
    s0 = MFMA32(t.h0[ks], Ql[ks], s0);
    s1 = MFMA32(t.h1[ks], Qh[ks], s1);
    s1 = MFMA32(t.l1[ks], Qh[ks], s1);
    s1 = MFMA32(t.h1[ks], Ql[ks], s1);
  }
}

// ---------------- fused attention: swapped 32x32, zero-LDS, double-buffered regs ----------------
// bh-major decode: consecutive blockIdx -> different bh -> bh%8 pins each head set to one XCD.
__global__ __launch_bounds__(64,2) void attn_kernel(
    const __hip_bfloat16* __restrict__ qh, const __hip_bfloat16* __restrict__ ql,
    const __hip_bfloat16* __restrict__ kh, const __hip_bfloat16* __restrict__ kl,
    const __hip_bfloat16* __restrict__ vT,
    float* __restrict__ wout,
    __hip_bfloat16* __restrict__ attnh, __hip_bfloat16* __restrict__ attnl)
{
  const int lane = threadIdx.x & 63;
  const int col = lane & 31;
  const int hi  = lane >> 5;
  const int bh = blockIdx.x % 24, qt = blockIdx.x / 24;

  const __hip_bfloat16* qr_h = qh + ((size_t)bh*2048 + qt*32 + col)*64 + hi*8;
  const __hip_bfloat16* qr_l = ql + ((size_t)bh*2048 + qt*32 + col)*64 + hi*8;
  s16x8 Qh[4], Ql[4];
  #pragma unroll
  for (int ks = 0; ks < 4; ++ks){
    Qh[ks] = *(const s16x8*)(qr_h + ks*16);
    Ql[ks] = *(const s16x8*)(qr_l + ks*16);
  }

  const __hip_bfloat16* kb_h = kh + (size_t)bh*2048*64;
  const __hip_bfloat16* kb_l = kl + (size_t)bh*2048*64;

  float m_run = -INFINITY, l_run = 0.f;

  auto s1body = [&](const KT& t){
    f32x16 s0, s1;
    kt_mfma(s0, s1, t, Qh, Ql);
    float mx = fmaxf(s0[0], s0[1]);
    #pragma unroll
    for (int e = 2; e < 16; ++e) mx = fmaxf(mx, s0[e]);
    #pragma unroll
    for (int e = 0; e < 16; ++e) mx = fmaxf(mx, s1[e]);
    float mn = fmaxf(m_run, mx);
    float sum = 0.f;
    #pragma unroll
    for (int e = 0; e < 16; ++e) sum += exp2f(s0[e]-mn);
    #pragma unroll
    for (int e = 0; e < 16; ++e) sum += exp2f(s1[e]-mn);
    l_run = l_run*exp2f(m_run-mn) + sum;
    m_run = mn;
  };

  KT ta, tb;
  // ---- sweep 1: online max/sum, double-buffered K prefetch ----
  kt_load(ta, kb_h, kb_l, 0, col, hi);
  for (int kt = 0; kt < 32; kt += 2){
    kt_load(tb, kb_h, kb_l, kt+1, col, hi);
    s1body(ta);
    kt_load(ta, kb_h, kb_l, (kt+2)&31, col, hi);
    s1body(tb);
  }
  {
    float mo = __shfl_xor(m_run, 32);
    float lo = __shfl_xor(l_run, 32);
    float mt = fmaxf(m_run, mo);
    l_run = l_run*exp2f(m_run-mt) + lo*exp2f(mo-mt);
    m_run = mt;
  }
  const float rl = 1.0f / l_run;

  // ---- sweep 2: recompute (bitwise identical), write weights, PV ----
  f32x16 pv0, pv1;
  #pragma unroll
  for (int e = 0; e < 16; ++e){ pv0[e] = 0.f; pv1[e] = 0.f; }
  const __hip_bfloat16* vb = vT + (size_t)bh*64*2048;
  float* wq = wout + (((size_t)bh*2048 + qt*32 + col)*2048);

  auto s2body = [&](const KT& t, int kt){
    s16x8 vv[4][2];
    #pragma unroll
    for (int ww = 0; ww < 4; ++ww){
      #pragma unroll
      for (int dt = 0; dt < 2; ++dt){
        vv[ww][dt] = *(const s16x8*)(vb + ((size_t)(dt*32+col)*2048 + kt*64 + ww*16 + hi*8));
      }
    }
    f32x16 s0, s1;
    kt_mfma(s0, s1, t, Qh, Ql);
    #pragma unroll
    for (int e = 0; e < 16; ++e){
      s0[e] = exp2f(s0[e]-m_run)*rl;
      s1[e] = exp2f(s1[e]-m_run)*rl;
    }
    float* wk = wq + kt*64;
    #pragma unroll
    for (int rq = 0; rq < 4; ++rq){
      float4 f0 = make_float4(s0[rq*4+0], s0[rq*4+1], s0[rq*4+2], s0[rq*4+3]);
      float4 f1 = make_float4(s1[rq*4+0], s1[rq*4+1], s1[rq*4+2], s1[rq*4+3]);
      *(float4*)(wk + rq*8 + hi*4)      = f0;
      *(float4*)(wk + 32 + rq*8 + hi*4) = f1;
    }
    #pragma unroll
    for (int ww = 0; ww < 4; ++ww){
      int e0 = (ww&1)*8;
      float a0,a1,a2,a3,a4,a5,a6,a7;
      if (ww < 2){ a0=s0[e0+0];a1=s0[e0+1];a2=s0[e0+2];a3=s0[e0+3];
                   a4=s0[e0+4];a5=s0[e0+5];a6=s0[e0+6];a7=s0[e0+7]; }
      else       { a0=s1[e0+0];a1=s1[e0+1];a2=s1[e0+2];a3=s1[e0+3];
                   a4=s1[e0+4];a5=s1[e0+5];a6=s1[e0+6];a7=s1[e0+7]; }
      unsigned wa = pack2(a0,a1);
      unsigned wb = pack2(a2,a3);
      unsigned wc = pack2(a4,a5);
      unsigned wd = pack2(a6,a7);
      plane32swap(wa, wc);
      plane32swap(wb, wd);
      union { unsigned u[4]; s16x8 v; } cv;
      cv.u[0]=wa; cv.u[1]=wb; cv.u[2]=wc; cv.u[3]=wd;
      pv0 = MFMA32(cv.v, vv[ww][0], pv0);
      pv1 = MFMA32(cv.v, vv[ww][1], pv1);
    }
  };

  kt_load(ta, kb_h, kb_l, 0, col, hi);
  for (int kt = 0; kt < 32; kt += 2){
    kt_load(tb, kb_h, kb_l, kt+1, col, hi);
    s2body(ta, kt);
    kt_load(ta, kb_h, kb_l, (kt+2)&31, col, hi);
    s2body(tb, kt+1);
  }

  // ---- epilogue ----
  const int b_ = bh / 12, hh = bh % 12;
  #pragma unroll
  for (int e = 0; e < 16; ++e){
    int qrow = qt*32 + (e&3) + 8*(e>>2) + 4*hi;
    size_t base = ((size_t)b_*2048 + qrow)*768 + hh*64;
    __hip_bfloat16 h0, l0, h1, l1;
    split2(pv0[e], h0, l0);
    split2(pv1[e], h1, l1);
    attnh[base + col]      = h0; attnl[base + col]      = l0;
    attnh[base + 32 + col] = h1; attnl[base + 32 + col] = l1;
  }
}

// ---------------- launch ----------------
extern "C" void kernel_launch(void* const* d_in, const int* in_sizes, int n_in,
                              void* d_out, int out_size, void* d_ws, size_t ws_size,
                              hipStream_t stream){
  const float* Q  = (const float*)d_in[0];
  const float* Kx = (const float*)d_in[1];
  const float* V  = (const float*)d_in[2];
  const float* Wq = (const float*)d_in[3];
  const float* bq = (const float*)d_in[4];
  const float* Wk = (const float*)d_in[5];
  const float* bk = (const float*)d_in[6];
  const float* Wv = (const float*)d_in[7];
  const float* bv = (const float*)d_in[8];
  const float* Wo = (const float*)d_in[9];
  const float* bo = (const float*)d_in[10];

  float* out = (float*)d_out;
  float* wts = out + (size_t)2*2048*768;

  char* cur = (char*)d_ws;
  auto alloc = [&](size_t elems)->__hip_bfloat16*{
    __hip_bfloat16* p = (__hip_bfloat16*)cur;
    cur += ((elems*2 + 255) & ~(size_t)255);
    return p;
  };
  const size_t NE = (size_t)4096*768;
  const size_t WE = (size_t)768*768;

  __hip_bfloat16 *QIh=alloc(NE), *QIl=alloc(NE), *KIh=alloc(NE), *KIl=alloc(NE),
                 *VIh=alloc(NE), *VIl=alloc(NE);
  __hip_bfloat16 *Wqh=alloc(WE), *Wql=alloc(WE), *Wkh=alloc(WE), *Wkl=alloc(WE),
                 *Wvh=alloc(WE), *Wvl=alloc(WE), *Woh=alloc(WE), *Wol=alloc(WE);
  __hip_bfloat16 *qhp=alloc(NE), *qlp=alloc(NE), *khp=alloc(NE), *klp=alloc(NE),
                 *vTp=alloc(NE);
  __hip_bfloat16 *ath=alloc(NE), *atl=alloc(NE);

  // fused split of all 7 fp32 inputs
  split_all<<<11520, 256, 0, stream>>>(Q, Kx, V, Wq, Wk, Wv, Wo,
      QIh,QIl, KIh,KIl, VIh,VIl, Wqh,Wql, Wkh,Wkl, Wvh,Wvl, Woh,Wol);

  // log2-domain softmax: bake log2(e)/8 into the Q projection scale
  gemm_nt<<<384, 256, 0, stream>>>(QIh,QIl,Wqh,Wql,bq, 0.18033688011112042f, 0, qhp,qlp,nullptr);
  gemm_nt<<<384, 256, 0, stream>>>(KIh,KIl,Wkh,Wkl,bk, 1.0f,   1, khp,klp,nullptr);
  gemm_nt<<<384, 256, 0, stream>>>(VIh,VIl,Wvh,Wvl,bv, 1.0f,   2, vTp,nullptr,nullptr);

  attn_kernel<<<1536, 64, 0, stream>>>(qhp,qlp,khp,klp,vTp, wts, ath, atl);

  gemm_nt<<<384, 256, 0, stream>>>(ath,atl,Woh,Wol,bo, 1.0f, 3, nullptr,nullptr,out);
}

// Round 6
// 339.950 us; speedup vs baseline: 1.3387x; 1.2770x over previous
//
#include <hip/hip_runtime.h>
#include <hip/hip_bf16.h>

typedef __attribute__((ext_vector_type(4)))  float f32x4;
typedef __attribute__((ext_vector_type(16))) float f32x16;
typedef __attribute__((ext_vector_type(8)))  short s16x8;

#define MFMA(a,b,c)   __builtin_amdgcn_mfma_f32_16x16x32_bf16(a,b,c,0,0,0)
#define MFMA32(a,b,c) __builtin_amdgcn_mfma_f32_32x32x16_bf16(a,b,c,0,0,0)

__device__ __forceinline__ void gll16(const void* gptr, void* lptr){
  auto g = (const __attribute__((address_space(1))) unsigned int*)gptr;
  auto l = (__attribute__((address_space(3))) unsigned int*)lptr;
  __builtin_amdgcn_global_load_lds(g, l, 16, 0, 0);
}

__device__ __forceinline__ void split2(float x, __hip_bfloat16& h, __hip_bfloat16& l){
  h = __float2bfloat16(x);
  l = __float2bfloat16(x - __bfloat162float(h));
}

__device__ __forceinline__ unsigned short bf16bits(float x){
  __hip_bfloat16 h = __float2bfloat16(x);
  return *reinterpret_cast<unsigned short*>(&h);
}
__device__ __forceinline__ unsigned pack2(float lo, float hi){
  return (unsigned)bf16bits(lo) | ((unsigned)bf16bits(hi) << 16);
}
__device__ __forceinline__ void plane32swap(unsigned &a, unsigned &b){
  asm volatile("v_permlane32_swap_b32 %0, %1" : "+v"(a), "+v"(b));
}

// ---------------- fused input split: fp32 -> (hi, lo) bf16, float4-vectorized ----------------
__global__ __launch_bounds__(256) void split_all(
  const float* __restrict__ Q, const float* __restrict__ K, const float* __restrict__ V,
  const float* __restrict__ Wq, const float* __restrict__ Wk,
  const float* __restrict__ Wv, const float* __restrict__ Wo,
  __hip_bfloat16* __restrict__ QIh, __hip_bfloat16* __restrict__ QIl,
  __hip_bfloat16* __restrict__ KIh, __hip_bfloat16* __restrict__ KIl,
  __hip_bfloat16* __restrict__ VIh, __hip_bfloat16* __restrict__ VIl,
  __hip_bfloat16* __restrict__ Wqh, __hip_bfloat16* __restrict__ Wql,
  __hip_bfloat16* __restrict__ Wkh, __hip_bfloat16* __restrict__ Wkl,
  __hip_bfloat16* __restrict__ Wvh, __hip_bfloat16* __restrict__ Wvl,
  __hip_bfloat16* __restrict__ Woh, __hip_bfloat16* __restrict__ Wol)
{
  const int NE4 = 786432, WE4 = 147456;
  int i = blockIdx.x*256 + threadIdx.x;
  const float* src; __hip_bfloat16 *dh, *dl; int off;
  if (i < 3*NE4){
    int seg = i / NE4; off = i - seg*NE4;
    src = seg==0 ? Q   : (seg==1 ? K   : V);
    dh  = seg==0 ? QIh : (seg==1 ? KIh : VIh);
    dl  = seg==0 ? QIl : (seg==1 ? KIl : VIl);
  } else {
    int j = i - 3*NE4; int seg = j / WE4; off = j - seg*WE4;
    src = seg==0 ? Wq  : (seg==1 ? Wk  : (seg==2 ? Wv  : Wo));
    dh  = seg==0 ? Wqh : (seg==1 ? Wkh : (seg==2 ? Wvh : Woh));
    dl  = seg==0 ? Wql : (seg==1 ? Wkl : (seg==2 ? Wvl : Wol));
  }
  float4 x = ((const float4*)src)[off];
  __hip_bfloat16 h0,l0,h1,l1,h2,l2,h3,l3;
  split2(x.x,h0,l0); split2(x.y,h1,l1); split2(x.z,h2,l2); split2(x.w,h3,l3);
  union { __hip_bfloat16 b[4]; ushort4 u; } H, L;
  H.b[0]=h0; H.b[1]=h1; H.b[2]=h2; H.b[3]=h3;
  L.b[0]=l0; L.b[1]=l1; L.b[2]=l2; L.b[3]=l3;
  *(ushort4*)(dh + (size_t)off*4) = H.u;
  *(ushort4*)(dl + (size_t)off*4) = L.u;
}

// ---------------- NT GEMM (A[4096x768] x B[768x768]^T), split-bf16 ----------------
// mode 0: Q epilogue (scale, split -> [B,H,S,d] hi/lo)
// mode 1: K epilogue (hi only -> [B,H,S,d])
// mode 2: V epilogue (bf16 -> [B,H,d,S] transposed)
// mode 3: O epilogue (fp32 -> [4096,768])
__global__ __launch_bounds__(256) void gemm_nt(
    const __hip_bfloat16* __restrict__ Ah, const __hip_bfloat16* __restrict__ Al,
    const __hip_bfloat16* __restrict__ Bh, const __hip_bfloat16* __restrict__ Bl,
    const float* __restrict__ bias, float scale, int mode,
    __hip_bfloat16* __restrict__ o_hi, __hip_bfloat16* __restrict__ o_lo,
    float* __restrict__ o_f)
{
  __shared__ __align__(16) __hip_bfloat16 sAh[128*64];
  __shared__ __align__(16) __hip_bfloat16 sAl[128*64];
  __shared__ __align__(16) __hip_bfloat16 sBh[64*64];
  __shared__ __align__(16) __hip_bfloat16 sBl[64*64];

  const int tid = threadIdx.x;
  const int w = tid >> 6, lane = tid & 63, r = lane & 15, g = lane >> 4;
  const int tm = blockIdx.x / 12, tn = blockIdx.x % 12;

  const char* gA_h = (const char*)Ah + (size_t)tm*128*768*2;
  const char* gA_l = (const char*)Al + (size_t)tm*128*768*2;
  const char* gB_h = (const char*)Bh + (size_t)tn*64*768*2;
  const char* gB_l = (const char*)Bl + (size_t)tn*64*768*2;

  f32x4 acc[2][4] = {};

  for (int kb = 0; kb < 768; kb += 64){
    __syncthreads();
    #pragma unroll
    for (int i = 0; i < 4; ++i){
      int lb = i*4096 + tid*16;
      int row = lb >> 7, colb = lb & 127;
      gll16(gA_h + (size_t)row*1536 + kb*2 + colb, (char*)sAh + i*4096 + w*1024);
      gll16(gA_l + (size_t)row*1536 + kb*2 + colb, (char*)sAl + i*4096 + w*1024);
    }
    #pragma unroll
    for (int i = 0; i < 2; ++i){
      int lb = i*4096 + tid*16;
      int row = lb >> 7, colb = lb & 127;
      gll16(gB_h + (size_t)row*1536 + kb*2 + colb, (char*)sBh + i*4096 + w*1024);
      gll16(gB_l + (size_t)row*1536 + kb*2 + colb, (char*)sBl + i*4096 + w*1024);
    }
    __syncthreads();
    #pragma unroll
    for (int c = 0; c < 2; ++c){
      s16x8 a_h[2], a_l[2];
      #pragma unroll
      for (int i = 0; i < 2; ++i){
        int off = (w*32 + i*16 + r)*64 + c*32 + g*8;
        a_h[i] = *(const s16x8*)(sAh + off);
        a_l[i] = *(const s16x8*)(sAl + off);
      }
      #pragma unroll
      for (int j = 0; j < 4; ++j){
        int off = (j*16 + r)*64 + c*32 + g*8;
        s16x8 b_h = *(const s16x8*)(sBh + off);
        s16x8 b_l = *(const s16x8*)(sBl + off);
        #pragma unroll
        for (int i = 0; i < 2; ++i){
          acc[i][j] = MFMA(a_h[i], b_h, acc[i][j]);
          acc[i][j] = MFMA(a_l[i], b_h, acc[i][j]);
          acc[i][j] = MFMA(a_h[i], b_l, acc[i][j]);
        }
      }
    }
  }

  #pragma unroll
  for (int i = 0; i < 2; ++i){
    #pragma unroll
    for (int j = 0; j < 4; ++j){
      #pragma unroll
      for (int e = 0; e < 4; ++e){
        int m = tm*128 + w*32 + i*16 + g*4 + e;
        int n = tn*64 + j*16 + r;
        float v = acc[i][j][e] + bias[n];
        if (mode == 0){
          v *= scale;
          __hip_bfloat16 h, l; split2(v, h, l);
          int b = m >> 11, s = m & 2047;
          size_t idx = ((size_t)(b*12 + (n>>6))*2048 + s)*64 + (n & 63);
          o_hi[idx] = h; o_lo[idx] = l;
        } else if (mode == 1){
          int b = m >> 11, s = m & 2047;
          size_t idx = ((size_t)(b*12 + (n>>6))*2048 + s)*64 + (n & 63);
          o_hi[idx] = __float2bfloat16(v);
        } else if (mode == 2){
          int b = m >> 11, s = m & 2047;
          size_t idx = ((size_t)(b*12 + (n>>6))*64 + (n & 63))*2048 + s;
          o_hi[idx] = __float2bfloat16(v);
        } else {
          o_f[(size_t)m*768 + n] = v;
        }
      }
    }
  }
}

// ---------------- fused attention ----------------
// block = 256 thr (4 waves), grid = 24 bh * 64 qt. Each block: 32 q-rows, all 2048 keys.
// Wave w owns keys [w*512, (w+1)*512) in 16 chunks of 32. Softmax reference m=0.
// Sweep 1: l = sum exp2(s) (1-term QK). Sweep 2: p = exp2(s) (2-term QK),
// weights = p*rl (q-row = col, S^T layout), PV with unnormalized bf16 p.
// PV D-fragment has q-row = (e&3)+8*(e>>2)+4*hi -> epilogue MUST use ldsRL[qsub],
// not the thread's own rl (that was the R5 bug).
__global__ __launch_bounds__(256,4) void attn_kernel(
    const __hip_bfloat16* __restrict__ qh, const __hip_bfloat16* __restrict__ ql,
    const __hip_bfloat16* __restrict__ kh,
    const __hip_bfloat16* __restrict__ vT,
    float* __restrict__ wout,
    __hip_bfloat16* __restrict__ attnh, __hip_bfloat16* __restrict__ attnl)
{
  __shared__ float ldsPV[32*128];   // [e][buf*64+lane], 16 KB
  __shared__ float ldsL[128];
  __shared__ float ldsRL[32];       // 1/l per q-row (index = row within the 32-row tile)

  const int tid  = threadIdx.x;
  const int w    = tid >> 6;
  const int lane = tid & 63;
  const int col  = lane & 31;
  const int hi   = lane >> 5;
  const int bh = blockIdx.x % 24, qt = blockIdx.x / 24;

  // Q fragments (rows qt*32 + col), k-slice ks*16 + hi*8
  const __hip_bfloat16* qr_h = qh + ((size_t)bh*2048 + qt*32 + col)*64 + hi*8;
  const __hip_bfloat16* qr_l = ql + ((size_t)bh*2048 + qt*32 + col)*64 + hi*8;
  s16x8 Qh[4], Ql[4];
  #pragma unroll
  for (int ks = 0; ks < 4; ++ks){
    Qh[ks] = *(const s16x8*)(qr_h + ks*16);
    Ql[ks] = *(const s16x8*)(qr_l + ks*16);
  }

  const __hip_bfloat16* kb = kh + (size_t)bh*2048*64;     // [key][64]
  const __hip_bfloat16* vb = vT + (size_t)bh*64*2048;     // [d][key]

  // ---- sweep 1: l only (1-term QK) ----
  float ps0=0.f, ps1=0.f, ps2=0.f, ps3=0.f;
  for (int c = 0; c < 16; ++c){
    const int key0 = (w*16 + c)*32;
    const __hip_bfloat16* kr = kb + ((size_t)key0 + col)*64 + hi*8;
    s16x8 kf[4];
    #pragma unroll
    for (int ks = 0; ks < 4; ++ks) kf[ks] = *(const s16x8*)(kr + ks*16);
    f32x16 s0;
    #pragma unroll
    for (int e = 0; e < 16; ++e) s0[e] = 0.f;
    #pragma unroll
    for (int ks = 0; ks < 4; ++ks) s0 = MFMA32(kf[ks], Qh[ks], s0);
    #pragma unroll
    for (int e = 0; e < 16; e += 4){
      ps0 += exp2f(s0[e+0]); ps1 += exp2f(s0[e+1]);
      ps2 += exp2f(s0[e+2]); ps3 += exp2f(s0[e+3]);
    }
  }
  float l_w = (ps0+ps1) + (ps2+ps3);
  l_w += __shfl_xor(l_w, 32);
  if (lane < 32) ldsL[w*32 + col] = l_w;
  __syncthreads();
  const float l_tot = (ldsL[col] + ldsL[32+col]) + (ldsL[64+col] + ldsL[96+col]);
  const float rl = 1.0f / l_tot;
  if (tid < 32) ldsRL[tid] = rl;   // q-row = col = tid for wave 0

  // ---- sweep 2: p, weights, PV ----
  f32x16 pv0, pv1;
  #pragma unroll
  for (int e = 0; e < 16; ++e){ pv0[e]=0.f; pv1[e]=0.f; }
  float* wq = wout + ((size_t)bh*2048 + qt*32 + col)*2048;

  for (int c = 0; c < 16; ++c){
    const int key0 = (w*16 + c)*32;
    const __hip_bfloat16* kr = kb + ((size_t)key0 + col)*64 + hi*8;
    s16x8 kf[4];
    #pragma unroll
    for (int ks = 0; ks < 4; ++ks) kf[ks] = *(const s16x8*)(kr + ks*16);
    // V fragments for this chunk: row d = dt*32+col, keys key0 + ww*16 + hi*8
    s16x8 vv[2][2];
    #pragma unroll
    for (int ww = 0; ww < 2; ++ww)
      #pragma unroll
      for (int dt = 0; dt < 2; ++dt)
        vv[ww][dt] = *(const s16x8*)(vb + ((size_t)(dt*32+col)*2048 + key0 + ww*16 + hi*8));

    f32x16 s0;
    #pragma unroll
    for (int e = 0; e < 16; ++e) s0[e] = 0.f;
    #pragma unroll
    for (int ks = 0; ks < 4; ++ks){
      s0 = MFMA32(kf[ks], Qh[ks], s0);
      s0 = MFMA32(kf[ks], Ql[ks], s0);
    }
    #pragma unroll
    for (int e = 0; e < 16; ++e) s0[e] = exp2f(s0[e]);   // unnormalized p, q-row = col

    // weights: key = key0 + rq*8 + hi*4 + j, q-row = col  (S^T layout: correct rl)
    float* wk = wq + key0;
    #pragma unroll
    for (int rq = 0; rq < 4; ++rq){
      float4 f = make_float4(s0[rq*4+0]*rl, s0[rq*4+1]*rl,
                             s0[rq*4+2]*rl, s0[rq*4+3]*rl);
      *(float4*)(wk + rq*8 + hi*4) = f;
    }

    // pack p -> bf16 A-frags per 16-key window, PV
    #pragma unroll
    for (int ww = 0; ww < 2; ++ww){
      const int e0 = ww*8;
      unsigned wa = pack2(s0[e0+0], s0[e0+1]);
      unsigned wb = pack2(s0[e0+2], s0[e0+3]);
      unsigned wc = pack2(s0[e0+4], s0[e0+5]);
      unsigned wd = pack2(s0[e0+6], s0[e0+7]);
      plane32swap(wa, wc);
      plane32swap(wb, wd);
      union { unsigned u[4]; s16x8 v; } cv;
      cv.u[0]=wa; cv.u[1]=wb; cv.u[2]=wc; cv.u[3]=wd;
      pv0 = MFMA32(cv.v, vv[ww][0], pv0);
      pv1 = MFMA32(cv.v, vv[ww][1], pv1);
    }
  }

  // ---- merge PV across the 4 waves (tree via LDS) ----
  if (w >= 2){
    const int buf = w - 2;
    #pragma unroll
    for (int e = 0; e < 16; ++e){
      ldsPV[(e)   *128 + buf*64 + lane] = pv0[e];
      ldsPV[(16+e)*128 + buf*64 + lane] = pv1[e];
    }
  }
  __syncthreads();
  if (w < 2){
    #pragma unroll
    for (int e = 0; e < 16; ++e){
      pv0[e] += ldsPV[(e)   *128 + w*64 + lane];
      pv1[e] += ldsPV[(16+e)*128 + w*64 + lane];
    }
  }
  __syncthreads();
  if (w == 1){
    #pragma unroll
    for (int e = 0; e < 16; ++e){
      ldsPV[(e)   *128 + lane] = pv0[e];
      ldsPV[(16+e)*128 + lane] = pv1[e];
    }
  }
  __syncthreads();
  if (w == 0){
    #pragma unroll
    for (int e = 0; e < 16; ++e){
      pv0[e] += ldsPV[(e)   *128 + lane];
      pv1[e] += ldsPV[(16+e)*128 + lane];
    }
    const int b_ = bh / 12, hh = bh % 12;
    #pragma unroll
    for (int e = 0; e < 16; ++e){
      int qsub = (e&3) + 8*(e>>2) + 4*hi;        // q-row of THIS register (PV D-layout)
      float re = ldsRL[qsub];                     // matching 1/l  (R5 bug: used rl of q-row col)
      int qrow = qt*32 + qsub;
      size_t base = ((size_t)b_*2048 + qrow)*768 + hh*64;
      __hip_bfloat16 h0, l0, h1, l1;
      split2(pv0[e]*re, h0, l0);
      split2(pv1[e]*re, h1, l1);
      attnh[base + col]      = h0; attnl[base + col]      = l0;
      attnh[base + 32 + col] = h1; attnl[base + 32 + col] = l1;
    }
  }
}

// ---------------- launch ----------------
extern "C" void kernel_launch(void* const* d_in, const int* in_sizes, int n_in,
                              void* d_out, int out_size, void* d_ws, size_t ws_size,
                              hipStream_t stream){
  const float* Q  = (const float*)d_in[0];
  const float* Kx = (const float*)d_in[1];
  const float* V  = (const float*)d_in[2];
  const float* Wq = (const float*)d_in[3];
  const float* bq = (const float*)d_in[4];
  const float* Wk = (const float*)d_in[5];
  const float* bk = (const float*)d_in[6];
  const float* Wv = (const float*)d_in[7];
  const float* bv = (const float*)d_in[8];
  const float* Wo = (const float*)d_in[9];
  const float* bo = (const float*)d_in[10];

  float* out = (float*)d_out;
  float* wts = out + (size_t)2*2048*768;

  char* cur = (char*)d_ws;
  auto alloc = [&](size_t elems)->__hip_bfloat16*{
    __hip_bfloat16* p = (__hip_bfloat16*)cur;
    cur += ((elems*2 + 255) & ~(size_t)255);
    return p;
  };
  const size_t NE = (size_t)4096*768;
  const size_t WE = (size_t)768*768;

  __hip_bfloat16 *QIh=alloc(NE), *QIl=alloc(NE), *KIh=alloc(NE), *KIl=alloc(NE),
                 *VIh=alloc(NE), *VIl=alloc(NE);
  __hip_bfloat16 *Wqh=alloc(WE), *Wql=alloc(WE), *Wkh=alloc(WE), *Wkl=alloc(WE),
                 *Wvh=alloc(WE), *Wvl=alloc(WE), *Woh=alloc(WE), *Wol=alloc(WE);
  __hip_bfloat16 *qhp=alloc(NE), *qlp=alloc(NE), *khp=alloc(NE), *klp=alloc(NE),
                 *vTp=alloc(NE);
  __hip_bfloat16 *ath=alloc(NE), *atl=alloc(NE);

  split_all<<<11520, 256, 0, stream>>>(Q, Kx, V, Wq, Wk, Wv, Wo,
      QIh,QIl, KIh,KIl, VIh,VIl, Wqh,Wql, Wkh,Wkl, Wvh,Wvl, Woh,Wol);

  // log2-domain softmax: bake log2(e)/8 into the Q projection scale
  gemm_nt<<<384, 256, 0, stream>>>(QIh,QIl,Wqh,Wql,bq, 0.18033688011112042f, 0, qhp,qlp,nullptr);
  gemm_nt<<<384, 256, 0, stream>>>(KIh,KIl,Wkh,Wkl,bk, 1.0f,   1, khp,klp,nullptr);
  gemm_nt<<<384, 256, 0, stream>>>(VIh,VIl,Wvh,Wvl,bv, 1.0f,   2, vTp,nullptr,nullptr);

  attn_kernel<<<1536, 256, 0, stream>>>(qhp,qlp,khp,vTp, wts, ath, atl);

  gemm_nt<<<384, 256, 0, stream>>>(ath,atl,Woh,Wol,bo, 1.0f, 3, nullptr,nullptr,out);
}